// Round 5
// baseline (436.527 us; speedup 1.0000x reference)
//
#include <hip/hip_runtime.h>

// CausalSelfAttention: B=2, S=2048, H=2048, NH=16, HD=128. f32 in/out, bf16 MFMA inside.
// R13: R12's B-direct reverted (L2 BW < LDS BW -> regression). Root cause across
// R10-R12: at BM=128/BN=256 the per-K-tile LDS demand (128KB rd + 48KB wr ~ 1900cy)
// exceeds MFMA work (1242cy) -> DS-bound at ~35% MfmaUtil regardless of schedule.
// R13 moves to the 256x256 tile (m201 regime): per tile MFMA 2483cy > DS ~2215cy
// -> compute-bound. 512 thr, 8 waves 2Mx4N, wave tile 128x64, acc[8][4], LDS 128KB
// (A 256x64 x2buf + B 256x64 x2buf). Schedule: 4 phases/K-tile, frag reads one
// phase ahead w/ counted lgkmcnt(4/8/4/0), 2 barriers/tile, stage(t+2) certified
// by vmcnt(8) one tile later, setprio around MFMA clusters, sched_barrier after
// every counted wait (rule #18). Swizzle (16B-slot XOR row&7, conflicts=0 measured),
// epilogue pack formulas, XCD clustering reused verbatim from verified rounds.
// QKV: 384 blocks (16m x 24n, 48/XCD); out-proj: 128 blocks.
// attn_kernel / convert_x / convert_wt(transpose) unchanged from R9/R11 (verified).

using bf16x8 = __attribute__((ext_vector_type(8))) short;
using bf16x4 = __attribute__((ext_vector_type(4))) short;
using f32x4  = __attribute__((ext_vector_type(4))) float;

#define S_LEN 2048
#define NHEAD 16
#define HDIM  128
#define HID   2048

__device__ __forceinline__ unsigned short f2bf(float f) {
    unsigned int u = __float_as_uint(f);
    u += 0x7fffu + ((u >> 16) & 1u);   // round-to-nearest-even
    return (unsigned short)(u >> 16);
}
__device__ __forceinline__ void gl2lds16(const void* g, void* l) {
    __builtin_amdgcn_global_load_lds(
        (const __attribute__((address_space(1))) void*)g,
        (__attribute__((address_space(3))) void*)l, 16, 0, 0);
}

// 16x16x16 bf16 MFMA, device-guarded (host pass must not reference the builtin).
__device__ __forceinline__ f32x4 pv_mfma(bf16x4 a, bf16x4 b, f32x4 c) {
#if defined(__HIP_DEVICE_COMPILE__)
#if __has_builtin(__builtin_amdgcn_mfma_f32_16x16x16bf16_1k)
    return __builtin_amdgcn_mfma_f32_16x16x16bf16_1k(a, b, c, 0, 0, 0);
#else
    asm("v_mfma_f32_16x16x16_bf16 %0, %1, %2, %0" : "+v"(c) : "v"(a), "v"(b));
    return c;
#endif
#else
    (void)a; (void)b;
    return c;
#endif
}

// ---------------------------------------------------------------- convert x: f32 -> bf16
__global__ void convert_x(const float* __restrict__ x, unsigned short* __restrict__ xb) {
    int i = (blockIdx.x * 256 + threadIdx.x) * 4;
    float4 v = *(const float4*)(x + i);
    ushort4 o;
    o.x = f2bf(v.x); o.y = f2bf(v.y); o.z = f2bf(v.z); o.w = f2bf(v.w);
    *(ushort4*)(xb + i) = o;
}

// ------------------------------------------------- convert+transpose weights: f32 -> bf16^T
__global__ void convert_wt(const float* __restrict__ w0, const float* __restrict__ w1,
                           const float* __restrict__ w2, const float* __restrict__ w3,
                           unsigned short* __restrict__ t0, unsigned short* __restrict__ t1,
                           unsigned short* __restrict__ t2, unsigned short* __restrict__ t3) {
    __shared__ float tile[64][65];
    int z = blockIdx.z;
    const float* src = (z == 0) ? w0 : (z == 1) ? w1 : (z == 2) ? w2 : w3;
    unsigned short* dst = (z == 0) ? t0 : (z == 1) ? t1 : (z == 2) ? t2 : t3;
    int r0 = blockIdx.y * 64, c0 = blockIdx.x * 64;
    int t = threadIdx.x;
    for (int i = t; i < 64 * 64; i += 256) {
        int r = i >> 6, c = i & 63;
        tile[r][c] = src[(size_t)(r0 + r) * HID + c0 + c];
    }
    __syncthreads();
    for (int i = t; i < 64 * 64; i += 256) {
        int r = i & 63, c = i >> 6;
        dst[(size_t)(c0 + c) * HID + r0 + r] = f2bf(tile[r][c]);
    }
}

// ---------------------------------------------------------------- GEMM 256x256 (R13)
// C[4096][N] = A @ Bt^T + bias; A,Bt bf16, fp32 acc.
// MODE 0: N=2048, f32 row-major to Cf (out-proj). Grid 128.
// MODE 1: N=6144 fused QKV (z = ncol>>11). Grid 384.
template <int MODE>
__launch_bounds__(512, 2)
__global__ void gemm256(const unsigned short* __restrict__ A,
                        const unsigned short* __restrict__ Bt0,
                        const unsigned short* __restrict__ Bt1,
                        const unsigned short* __restrict__ Bt2,
                        const float* __restrict__ bias0,
                        const float* __restrict__ bias1,
                        const float* __restrict__ bias2,
                        unsigned short* __restrict__ C0,
                        unsigned short* __restrict__ C1,
                        unsigned short* __restrict__ C2,
                        float* __restrict__ Cf) {
    // LDS 128KB: A 256x64 bf16 (32KB) x2buf + B 256x64 (32KB) x2buf.
    __shared__ __align__(16) unsigned short lds[65536];
    unsigned short* const A0 = lds;             // [0, 16384)
    unsigned short* const A1 = lds + 16384;
    unsigned short* const B0 = lds + 32768;
    unsigned short* const B1 = lds + 49152;

    const int CPX = (MODE == 1) ? 48 : 16;      // blocks per XCD
    int vb = (blockIdx.x & 7) * CPX + (blockIdx.x >> 3);
    int m0  = (vb & 15) * 256;
    int n0g = (vb >> 4) * 256;                  // global col (0..6143 fused)

    const unsigned short* Bt = Bt0;
    const float* bias = bias0;
    unsigned short* C = C0;
    int z = 0;
    if (MODE == 1) {
        z = n0g >> 11;
        if (z == 1) { Bt = Bt1; bias = bias1; C = C1; }
        else if (z == 2) { Bt = Bt2; bias = bias2; C = C2; }
    }
    int nb0 = n0g & 2047;                       // col within the z-matrix

    int tid = threadIdx.x;
    int lane = tid & 63;
    int wv_ = tid >> 6;
    int wr = wv_ >> 2, wc = wv_ & 3;            // 2x4 wave grid; wave tile 128x64
    int l15 = lane & 15, quad = lane >> 4;

    // ---- staging: 512 thr x 16B = 64 rows/issue; 4 issues per matrix per K-tile.
    // T2 pre-swizzled source (verified, conflicts=0): LDS slot s gets col (s^row&7).
    int tr = tid >> 3;
    int tc = ((tid & 7) ^ (tr & 7)) << 3;
    const unsigned short* gA = A  + (size_t)(m0  + tr) * HID + tc;
    const unsigned short* gB = Bt + (size_t)(nb0 + tr) * HID + tc;
    const int td8 = tid * 8;

    // ---- fragment ds_read offsets (read swizzle = store swizzle).
    int arow0 = (wr * 128 + l15) * 64;          // + mi*1024
    int brow0 = (wc * 64 + l15) * 64;           // + nj*1024
    int sw0 = ((quad ^ (l15 & 7)) << 3);        // kk=0
    int sw1 = (((4 + quad) ^ (l15 & 7)) << 3);  // kk=1

    f32x4 acc[8][4];
#pragma unroll
    for (int i = 0; i < 8; ++i)
#pragma unroll
        for (int j = 0; j < 4; ++j) acc[i][j] = (f32x4){0.f, 0.f, 0.f, 0.f};

    bf16x8 aX[4], aY[4], b0v[4], b1v[4];

#define STAGE(kt, AD, BD) do { int _kc = (kt) * 64;                          \
    gl2lds16(gA + _kc,             (AD) + td8);                              \
    gl2lds16(gA + 64 * HID + _kc,  (AD) + 4096 + td8);                       \
    gl2lds16(gA + 128 * HID + _kc, (AD) + 8192 + td8);                       \
    gl2lds16(gA + 192 * HID + _kc, (AD) + 12288 + td8);                      \
    gl2lds16(gB + _kc,             (BD) + td8);                              \
    gl2lds16(gB + 64 * HID + _kc,  (BD) + 4096 + td8);                       \
    gl2lds16(gB + 128 * HID + _kc, (BD) + 8192 + td8);                       \
    gl2lds16(gB + 192 * HID + _kc, (BD) + 12288 + td8); } while (0)

#define LDA4(dst, AD, QB, SW) do {                                           \
    dst[0] = *(const bf16x8*)((AD) + arow0 + ((QB) + 0) * 1024 + (SW));      \
    dst[1] = *(const bf16x8*)((AD) + arow0 + ((QB) + 1) * 1024 + (SW));      \
    dst[2] = *(const bf16x8*)((AD) + arow0 + ((QB) + 2) * 1024 + (SW));      \
    dst[3] = *(const bf16x8*)((AD) + arow0 + ((QB) + 3) * 1024 + (SW)); } while (0)

#define LDB4(dst, BD, SW) do {                                               \
    dst[0] = *(const bf16x8*)((BD) + brow0 + 0 * 1024 + (SW));               \
    dst[1] = *(const bf16x8*)((BD) + brow0 + 1 * 1024 + (SW));               \
    dst[2] = *(const bf16x8*)((BD) + brow0 + 2 * 1024 + (SW));               \
    dst[3] = *(const bf16x8*)((BD) + brow0 + 3 * 1024 + (SW)); } while (0)

#define MF16(Q, a, b) do {                                                   \
    __builtin_amdgcn_s_setprio(1);                                           \
    _Pragma("unroll")                                                        \
    for (int mi = 0; mi < 4; ++mi)                                           \
        _Pragma("unroll")                                                    \
        for (int nj = 0; nj < 4; ++nj)                                       \
            acc[(Q) * 4 + mi][nj] =                                          \
                __builtin_amdgcn_mfma_f32_16x16x32_bf16(a[mi], b[nj],        \
                                                        acc[(Q) * 4 + mi][nj], 0, 0, 0); \
    __builtin_amdgcn_s_setprio(0); } while (0)

#define SCHED0() __builtin_amdgcn_sched_barrier(0)
#define BAR()    do { asm volatile("" ::: "memory");                         \
                      __builtin_amdgcn_s_barrier();                          \
                      asm volatile("" ::: "memory"); } while (0)
#define W_LGKM(N) do { asm volatile("s_waitcnt lgkmcnt(" #N ")" ::: "memory"); SCHED0(); } while (0)
#define W_VM8()   do { asm volatile("s_waitcnt vmcnt(8)" ::: "memory");        SCHED0(); } while (0)

    // One K-tile in (AD,BD); next tile certified in (AN,BN_); stage ks into (AD,BD).
    // Entry invariant: ds outstanding = 8 {aX=q0kk0(AD), b0v=kk0(BD)};
    //                  vm outstanding = 8 {stage(t+1 -> AN,BN_)}.
#define TILE4(AD, BD, AN, BN_, ks) do {                                      \
    LDA4(aY, AD, 4, sw0);            /* ds: aX4,b0v4,aY4 = 12 */             \
    W_LGKM(4);                       /* aX,b0v ready */                      \
    MF16(0, aX, b0v);                                                        \
    LDA4(aX, AD, 0, sw1);                                                    \
    LDB4(b1v, BD, sw1);              /* ds: aY4 + 8 = 12 */                  \
    W_LGKM(8);                       /* aY ready */                          \
    MF16(1, aY, b0v);                                                        \
    LDA4(aY, AD, 4, sw1);            /* ds: aX4,b1v4,aY4 = 12 */             \
    W_LGKM(4);                       /* aX,b1v ready */                      \
    MF16(0, aX, b1v);                                                        \
    W_LGKM(0);                       /* aY ready; all my (AD,BD) reads done */\
    BAR();                           /* all waves done reading (AD,BD) */    \
    STAGE(ks, AD, BD);               /* vm: old 8 + new 8 = 16 */            \
    W_VM8();                         /* stage(t+1 -> AN,BN_) complete */     \
    BAR();                           /* (AN,BN_) certified for all */        \
    LDA4(aX, AN, 0, sw0);                                                    \
    LDB4(b0v, BN_, sw0);             /* 8 ds in flight for next tile */      \
    SCHED0();                                                                \
    MF16(1, aY, b1v);                /* rides over next-tile reads */        \
} while (0)

    // prologue: stage tiles 0,1; certify tile0; issue tile0 kk0 frags.
    STAGE(0, A0, B0);
    STAGE(1, A1, B1);
    W_VM8();
    BAR();
    LDA4(aX, A0, 0, sw0);
    LDB4(b0v, B0, sw0);

    for (int t = 0; t < 32; t += 2) {
        TILE4(A0, B0, A1, B1, (t + 2 < 32) ? t + 2 : 31);
        TILE4(A1, B1, A0, B0, (t + 3 < 32) ? t + 3 : 31);
    }
    asm volatile("s_waitcnt vmcnt(0) lgkmcnt(0)" ::: "memory");

#undef TILE4
#undef STAGE
#undef LDA4
#undef LDB4
#undef MF16
#undef SCHED0
#undef BAR
#undef W_LGKM
#undef W_VM8

    // ---- epilogue (pack formulas verbatim from R9-R12; wave tile now 128x64)
#pragma unroll
    for (int j = 0; j < 4; ++j) {
        int n = nb0 + wc * 64 + j * 16 + l15;
        float bn = bias[n];
#pragma unroll
        for (int i = 0; i < 8; ++i) {
            int mb = m0 + wr * 128 + i * 16 + quad * 4;   // base row, regs = mb..mb+3
            if (MODE == 1 && z == 2) {
                // V-pack: 4 regs = 4 consecutive keys (e=0..3) -> one ushort4.
                int b = mb >> 11, s = mb & 2047, h = n >> 7, d = n & 127;
                int kt = s >> 4, qv = (s >> 2) & 3, ct = d >> 4, lv = d & 15;
                size_t addr = ((((size_t)((b << 4) + h) * 128 + kt) * 4 + (ct >> 1)) * 4 + qv) * 128
                              + lv * 8 + (ct & 1) * 4;
                ushort4 o;
                o.x = f2bf(acc[i][j][0] + bn);
                o.y = f2bf(acc[i][j][1] + bn);
                o.z = f2bf(acc[i][j][2] + bn);
                o.w = f2bf(acc[i][j][3] + bn);
                *(ushort4*)&C[addr] = o;
            } else {
#pragma unroll
                for (int reg = 0; reg < 4; ++reg) {
                    int m = mb + reg;
                    float v = acc[i][j][reg] + bn;
                    if (MODE == 0) {
                        Cf[(size_t)m * HID + n] = v;
                    } else {
                        int b = m >> 11, s = m & 2047, h = n >> 7, d = n & 127;
                        if (z == 1) {
                            // K-pack: key=s -> (kt, lk); d -> (kk, qk, e)
                            int kt = s >> 4, lk = s & 15, kk = d >> 5, qk = (d >> 3) & 3, e = d & 7;
                            size_t addr = ((((size_t)((b << 4) + h) * 128 + kt) * 4 + kk) * 4 + qk) * 128
                                          + lk * 8 + e;
                            C[addr] = f2bf(v);
                        } else {
                            C[(size_t)(((b << 4) + h) * S_LEN + s) * HDIM + d] = f2bf(v);
                        }
                    }
                }
            }
        }
    }
}

// ---------------------------------------------------------------- flash attention (R9, unchanged)
__launch_bounds__(256, 4)
__global__ void attn_kernel(const unsigned short* __restrict__ Qg,
                            const unsigned short* __restrict__ Kp,
                            const unsigned short* __restrict__ Vp,
                            unsigned short* __restrict__ O) {
    int linear = blockIdx.y * 32 + blockIdx.x;   // 0..1023
    int xcd = linear & 7;
    int u = linear >> 3;                          // 0..127
    int bh = xcd * 4 + (u & 3);                   // 4 bh per XCD
    int j = u >> 2;                               // 0..31
    int b = bh >> 4, h = bh & 15;

    int tid = threadIdx.x, lane = tid & 63, w = tid >> 6;
    int l15 = lane & 15, quad = lane >> 4;

    int role = (w + (u >> 5)) & 3;                // per-CU-varying rotation
    int strip = (role < 2) ? (2 * j + role) : (126 - 2 * j + (role - 2));
    int r0 = strip * 16;

    const unsigned short* Qb = Qg + (size_t)bh * (S_LEN * HDIM);
    const unsigned short* Kb = Kp + (size_t)bh * 262144 + quad * 128 + l15 * 8;
    const unsigned short* Vb = Vp + (size_t)bh * 262144 + quad * 128 + l15 * 8;

    bf16x8 qf[4];
#pragma unroll
    for (int kk = 0; kk < 4; ++kk)
        qf[kk] = *(const bf16x8*)&Qb[(size_t)(r0 + l15) * HDIM + kk * 32 + quad * 8];

    f32x4 o_acc[8];
#pragma unroll
    for (int c = 0; c < 8; ++c) o_acc[c] = (f32x4){0.f, 0.f, 0.f, 0.f};
    float l_part = 0.f;

    const float k2 = 0.08838834764831845f * 1.4426950408889634f;  // scale*log2(e)

    int nkt = strip + 1;

    bf16x8 kA[4], kB[4], v[4];

#define LOADK(dst, t) do { size_t _o = (size_t)(t) * 2048;                         \
    dst[0] = *(const bf16x8*)&Kb[_o];                                              \
    dst[1] = *(const bf16x8*)&Kb[_o + 512];                                        \
    dst[2] = *(const bf16x8*)&Kb[_o + 1024];                                       \
    dst[3] = *(const bf16x8*)&Kb[_o + 1536]; } while (0)

#define LOADV(dst, t) do { size_t _o = (size_t)(t) * 2048;                         \
    dst[0] = *(const bf16x8*)&Vb[_o];                                              \
    dst[1] = *(const bf16x8*)&Vb[_o + 512];                                        \
    dst[2] = *(const bf16x8*)&Vb[_o + 1024];                                       \
    dst[3] = *(const bf16x8*)&Vb[_o + 1536]; } while (0)

#define VLO(x) __builtin_shufflevector(x, x, 0, 1, 2, 3)
#define VHI(x) __builtin_shufflevector(x, x, 4, 5, 6, 7)

#define TILE(kreg, t) do {                                                         \
    f32x4 st0 = (f32x4){0.f, 0.f, 0.f, 0.f};                                       \
    f32x4 st1 = (f32x4){0.f, 0.f, 0.f, 0.f};                                       \
    st0 = __builtin_amdgcn_mfma_f32_16x16x32_bf16(kreg[0], qf[0], st0, 0, 0, 0);   \
    st1 = __builtin_amdgcn_mfma_f32_16x16x32_bf16(kreg[1], qf[1], st1, 0, 0, 0);   \
    st0 = __builtin_amdgcn_mfma_f32_16x16x32_bf16(kreg[2], qf[2], st0, 0, 0, 0);   \
    st1 = __builtin_amdgcn_mfma_f32_16x16x32_bf16(kreg[3], qf[3], st1, 0, 0, 0);   \
    f32x4 stv = st0 + st1;                                                         \
    float p0, p1, p2, p3;                                                          \
    if ((t) == nkt - 1) {                                                          \
        p0 = (quad * 4 + 0 <= l15) ? exp2f(stv[0] * k2) : 0.f;                     \
        p1 = (quad * 4 + 1 <= l15) ? exp2f(stv[1] * k2) : 0.f;                     \
        p2 = (quad * 4 + 2 <= l15) ? exp2f(stv[2] * k2) : 0.f;                     \
        p3 = (quad * 4 + 3 <= l15) ? exp2f(stv[3] * k2) : 0.f;                     \
    } else {                                                                       \
        p0 = exp2f(stv[0] * k2); p1 = exp2f(stv[1] * k2);                          \
        p2 = exp2f(stv[2] * k2); p3 = exp2f(stv[3] * k2);                          \
    }                                                                              \
    l_part += (p0 + p1) + (p2 + p3);                                               \
    bf16x4 pf;                                                                     \
    pf[0] = (short)f2bf(p0); pf[1] = (short)f2bf(p1);                              \
    pf[2] = (short)f2bf(p2); pf[3] = (short)f2bf(p3);                              \
    o_acc[0] = pv_mfma(pf, VLO(v[0]), o_acc[0]);                                   \
    o_acc[1] = pv_mfma(pf, VHI(v[0]), o_acc[1]);                                   \
    o_acc[2] = pv_mfma(pf, VLO(v[1]), o_acc[2]);                                   \
    o_acc[3] = pv_mfma(pf, VHI(v[1]), o_acc[3]);                                   \
    o_acc[4] = pv_mfma(pf, VLO(v[2]), o_acc[4]);                                   \
    o_acc[5] = pv_mfma(pf, VHI(v[2]), o_acc[5]);                                   \
    o_acc[6] = pv_mfma(pf, VLO(v[3]), o_acc[6]);                                   \
    o_acc[7] = pv_mfma(pf, VHI(v[3]), o_acc[7]);                                   \
} while (0)

    LOADK(kA, 0);
    int kt = 0;
    while (true) {
        int ktn = (kt + 1 < nkt) ? kt + 1 : kt;
        LOADV(v, kt);
        LOADK(kB, ktn);
        TILE(kA, kt);
        if (++kt >= nkt) break;

        ktn = (kt + 1 < nkt) ? kt + 1 : kt;
        LOADV(v, kt);
        LOADK(kA, ktn);
        TILE(kB, kt);
        if (++kt >= nkt) break;
    }

#undef TILE
#undef LOADK
#undef LOADV
#undef VLO
#undef VHI

    l_part += __shfl_xor(l_part, 16, 64);
    l_part += __shfl_xor(l_part, 32, 64);

#pragma unroll
    for (int reg = 0; reg < 4; ++reg) {
        float l = __shfl(l_part, quad * 4 + reg, 64);
        float inv = 1.f / l;
        int srow = r0 + quad * 4 + reg;
        unsigned short* op = O + (size_t)(b * S_LEN + srow) * HID + h * HDIM;
#pragma unroll
        for (int ct = 0; ct < 8; ++ct)
            op[ct * 16 + l15] = f2bf(o_acc[ct][reg] * inv);
    }
}

// ---------------------------------------------------------------- launch
extern "C" void kernel_launch(void* const* d_in, const int* in_sizes, int n_in,
                              void* d_out, int out_size, void* d_ws, size_t ws_size,
                              hipStream_t stream) {
    (void)in_sizes; (void)n_in; (void)out_size; (void)ws_size;
    const float* x  = (const float*)d_in[0];
    const float* wq = (const float*)d_in[2];
    const float* bq = (const float*)d_in[3];
    const float* wk = (const float*)d_in[4];
    const float* bk = (const float*)d_in[5];
    const float* wv = (const float*)d_in[6];
    const float* bv = (const float*)d_in[7];
    const float* wo = (const float*)d_in[8];
    const float* bo = (const float*)d_in[9];
    float* out = (float*)d_out;

    unsigned short* ws = (unsigned short*)d_ws;
    const size_t WSZ = 4194304;
    unsigned short* wqT = ws;                // [0, 4M)   transposed bf16 weights
    unsigned short* wkT = ws + WSZ;          // [4M, 8M)
    unsigned short* wvT = ws + 2 * WSZ;      // [8M, 12M)
    unsigned short* woT = ws + 3 * WSZ;      // [12M, 16M)
    unsigned short* xb  = ws + 4 * WSZ;      // [16M, 24M)
    unsigned short* Ab  = ws + 4 * WSZ;      // aliases xb (dead after QKV gemm)
    unsigned short* Qb  = ws + 6 * WSZ;      // [24M, 32M)
    unsigned short* Kb  = ws + 8 * WSZ;      // [32M, 40M)  fragment-packed
    unsigned short* Vb  = ws + 10 * WSZ;     // [40M, 48M)  fragment-packed

    convert_x<<<dim3(8192), 256, 0, stream>>>(x, xb);
    convert_wt<<<dim3(32, 32, 4), 256, 0, stream>>>(wq, wk, wv, wo, wqT, wkT, wvT, woT);
    gemm256<1><<<dim3(384), 512, 0, stream>>>(xb, wqT, wkT, wvT, bq, bk, bv,
                                              Qb, Kb, Vb, nullptr);
    attn_kernel<<<dim3(32, 32), 256, 0, stream>>>(Qb, Kb, Vb, Ab);
    gemm256<0><<<dim3(128), 512, 0, stream>>>(Ab, woT, nullptr, nullptr,
                                              bo, nullptr, nullptr,
                                              nullptr, nullptr, nullptr, out);
}

// Round 6
// 395.016 us; speedup vs baseline: 1.1051x; 1.1051x over previous
//
#include <hip/hip_runtime.h>

// CausalSelfAttention: B=2, S=2048, H=2048, NH=16, HD=128. f32 in/out, bf16 MFMA inside.
// R14 = R13's 256-row tile + schedule, with GRID QUANTIZATION fixed (R13's loss):
//   R13: QKV 384 blocks = 1.5 rounds (25% idle), outproj 128 blocks = half machine.
//   R14: QKV 256x192 tile -> 16x32 = 512 blocks = EXACT 2 rounds. Weights wqT/wkT/wvT
//   are contiguous in ws -> fused [6144][2048] B; tiles may straddle Q/K/V, epilogue
//   selects z per column (zj=n>>11). Outproj 256x128 -> 16x16 = 256 = EXACT 1 round.
//   Schedule: R13's verified 4-phase counted-lgkm pipeline, waits re-derived for
//   NJ (B frags/wave) in {3,2}: lgkm 4 / 4+NJ / 4 / 0; stage NS=4+NJ ops, vmcnt(NS).
//   T2 16B-slot XOR swizzle (conflicts=0 measured), epilogue pack formulas, XCD
//   clustering (64/32 blk per XCD) verbatim from verified rounds.
// attn_kernel / convert_x / convert_wt unchanged from R9/R11 (verified).

using bf16x8 = __attribute__((ext_vector_type(8))) short;
using bf16x4 = __attribute__((ext_vector_type(4))) short;
using f32x4  = __attribute__((ext_vector_type(4))) float;

#define S_LEN 2048
#define NHEAD 16
#define HDIM  128
#define HID   2048

__device__ __forceinline__ unsigned short f2bf(float f) {
    unsigned int u = __float_as_uint(f);
    u += 0x7fffu + ((u >> 16) & 1u);   // round-to-nearest-even
    return (unsigned short)(u >> 16);
}
__device__ __forceinline__ void gl2lds16(const void* g, void* l) {
    __builtin_amdgcn_global_load_lds(
        (const __attribute__((address_space(1))) void*)g,
        (__attribute__((address_space(3))) void*)l, 16, 0, 0);
}

// 16x16x16 bf16 MFMA, device-guarded (host pass must not reference the builtin).
__device__ __forceinline__ f32x4 pv_mfma(bf16x4 a, bf16x4 b, f32x4 c) {
#if defined(__HIP_DEVICE_COMPILE__)
#if __has_builtin(__builtin_amdgcn_mfma_f32_16x16x16bf16_1k)
    return __builtin_amdgcn_mfma_f32_16x16x16bf16_1k(a, b, c, 0, 0, 0);
#else
    asm("v_mfma_f32_16x16x16_bf16 %0, %1, %2, %0" : "+v"(c) : "v"(a), "v"(b));
    return c;
#endif
#else
    (void)a; (void)b;
    return c;
#endif
}

// ---------------------------------------------------------------- convert x: f32 -> bf16
__global__ void convert_x(const float* __restrict__ x, unsigned short* __restrict__ xb) {
    int i = (blockIdx.x * 256 + threadIdx.x) * 4;
    float4 v = *(const float4*)(x + i);
    ushort4 o;
    o.x = f2bf(v.x); o.y = f2bf(v.y); o.z = f2bf(v.z); o.w = f2bf(v.w);
    *(ushort4*)(xb + i) = o;
}

// ------------------------------------------------- convert+transpose weights: f32 -> bf16^T
__global__ void convert_wt(const float* __restrict__ w0, const float* __restrict__ w1,
                           const float* __restrict__ w2, const float* __restrict__ w3,
                           unsigned short* __restrict__ t0, unsigned short* __restrict__ t1,
                           unsigned short* __restrict__ t2, unsigned short* __restrict__ t3) {
    __shared__ float tile[64][65];
    int z = blockIdx.z;
    const float* src = (z == 0) ? w0 : (z == 1) ? w1 : (z == 2) ? w2 : w3;
    unsigned short* dst = (z == 0) ? t0 : (z == 1) ? t1 : (z == 2) ? t2 : t3;
    int r0 = blockIdx.y * 64, c0 = blockIdx.x * 64;
    int t = threadIdx.x;
    for (int i = t; i < 64 * 64; i += 256) {
        int r = i >> 6, c = i & 63;
        tile[r][c] = src[(size_t)(r0 + r) * HID + c0 + c];
    }
    __syncthreads();
    for (int i = t; i < 64 * 64; i += 256) {
        int r = i & 63, c = i >> 6;
        dst[(size_t)(c0 + c) * HID + r0 + r] = f2bf(tile[r][c]);
    }
}

// ---- counted waits (asm literals need compile-time dispatch) -----------------
__device__ __forceinline__ void sched0() { __builtin_amdgcn_sched_barrier(0); }
__device__ __forceinline__ void w_lgkm4() { asm volatile("s_waitcnt lgkmcnt(4)" ::: "memory"); sched0(); }
__device__ __forceinline__ void w_lgkm0() { asm volatile("s_waitcnt lgkmcnt(0)" ::: "memory"); sched0(); }
template <int NJ> __device__ __forceinline__ void w_lgkm_4nj() {
    if constexpr (NJ == 3) { asm volatile("s_waitcnt lgkmcnt(7)" ::: "memory"); }
    else                   { asm volatile("s_waitcnt lgkmcnt(6)" ::: "memory"); }
    sched0();
}
template <int NJ> __device__ __forceinline__ void w_vm_ns() {
    if constexpr (NJ == 3) { asm volatile("s_waitcnt vmcnt(7)" ::: "memory"); }
    else                   { asm volatile("s_waitcnt vmcnt(6)" ::: "memory"); }
    sched0();
}
__device__ __forceinline__ void barx() {
    asm volatile("" ::: "memory");
    __builtin_amdgcn_s_barrier();
    asm volatile("" ::: "memory");
}

// ---------------------------------------------------------------- GEMM 256xBN (R14)
// C[4096][N] = A @ Bt^T + bias; A,Bt bf16, fp32 acc. BN = NJ*64.
// MODE 1: fused QKV, N=6144, Bt0 = contiguous [6144][2048]. NJ=3 -> grid 512 (2 rounds).
// MODE 0: out-proj, N=2048, f32 out. NJ=2 -> grid 256 (1 round).
template <int MODE, int NJ>
__launch_bounds__(512, 2)
__global__ void gemmT(const unsigned short* __restrict__ A,
                      const unsigned short* __restrict__ Bt0,
                      const float* __restrict__ bias0,
                      const float* __restrict__ bias1,
                      const float* __restrict__ bias2,
                      unsigned short* __restrict__ C0,
                      unsigned short* __restrict__ C1,
                      unsigned short* __restrict__ C2,
                      float* __restrict__ Cf) {
    constexpr int BN = NJ * 64;
    // LDS: A 256x64 (32KB) x2 + B BNx64 x2.  NJ=3: 112KB, NJ=2: 96KB -> 1 blk/CU.
    __shared__ __align__(16) unsigned short lds[2 * 16384 + 2 * NJ * 4096];
    unsigned short* const A0 = lds;
    unsigned short* const A1 = lds + 16384;
    unsigned short* const B0 = lds + 32768;
    unsigned short* const B1 = lds + 32768 + NJ * 4096;

    const int CPX = (MODE == 1) ? 64 : 32;      // blocks per XCD (bijective: nwg%8==0)
    int vb = (blockIdx.x & 7) * CPX + (blockIdx.x >> 3);
    int m0  = (vb & 15) * 256;
    int n0g = (vb >> 4) * BN;                   // fused col (0..6143 / 0..2047)

    int tid = threadIdx.x;
    int lane = tid & 63;
    int wv_ = tid >> 6;
    int wr = wv_ >> 2, wc = wv_ & 3;            // 2x4 wave grid; wave tile 128 x (NJ*16)
    int l15 = lane & 15, quad = lane >> 4;

    // ---- staging: 512 thr x 16B = 64 rows/issue. A: 4 issues, B: NJ issues.
    // T2 pre-swizzled source (verified, conflicts=0): LDS slot s gets col (s^row&7).
    int tr = tid >> 3;
    int tc = ((tid & 7) ^ (tr & 7)) << 3;
    const unsigned short* gA = A   + (size_t)(m0  + tr) * HID + tc;
    const unsigned short* gB = Bt0 + (size_t)(n0g + tr) * HID + tc;
    const int td8 = tid * 8;

    // ---- fragment ds_read offsets (read swizzle = store swizzle).
    int arow0 = (wr * 128 + l15) * 64;          // + mi*1024
    int brow0 = (wc * (16 * NJ) + l15) * 64;    // + nj*1024
    int sw0 = ((quad ^ (l15 & 7)) << 3);        // kk=0
    int sw1 = (((4 + quad) ^ (l15 & 7)) << 3);  // kk=1

    f32x4 acc[8][NJ];
#pragma unroll
    for (int i = 0; i < 8; ++i)
#pragma unroll
        for (int j = 0; j < NJ; ++j) acc[i][j] = (f32x4){0.f, 0.f, 0.f, 0.f};

    bf16x8 aX[4], aY[4], b0v[NJ], b1v[NJ];

#define STAGE(kt, AD, BD) do { int _kc = (kt) * 64;                          \
    gl2lds16(gA + _kc,             (AD) + td8);                              \
    gl2lds16(gA + 64 * HID + _kc,  (AD) + 4096 + td8);                       \
    gl2lds16(gA + 128 * HID + _kc, (AD) + 8192 + td8);                       \
    gl2lds16(gA + 192 * HID + _kc, (AD) + 12288 + td8);                      \
    _Pragma("unroll")                                                        \
    for (int _r = 0; _r < NJ; ++_r)                                          \
        gl2lds16(gB + (size_t)(_r * 64) * HID + _kc, (BD) + _r * 4096 + td8); } while (0)

#define LDA4(dst, AD, QB, SW) do {                                           \
    dst[0] = *(const bf16x8*)((AD) + arow0 + ((QB) + 0) * 1024 + (SW));      \
    dst[1] = *(const bf16x8*)((AD) + arow0 + ((QB) + 1) * 1024 + (SW));      \
    dst[2] = *(const bf16x8*)((AD) + arow0 + ((QB) + 2) * 1024 + (SW));      \
    dst[3] = *(const bf16x8*)((AD) + arow0 + ((QB) + 3) * 1024 + (SW)); } while (0)

#define LDB(dst, BD, SW) do {                                                \
    _Pragma("unroll")                                                        \
    for (int _n = 0; _n < NJ; ++_n)                                          \
        dst[_n] = *(const bf16x8*)((BD) + brow0 + _n * 1024 + (SW)); } while (0)

#define MF(Q, a, b) do {                                                     \
    __builtin_amdgcn_s_setprio(1);                                           \
    _Pragma("unroll")                                                        \
    for (int mi = 0; mi < 4; ++mi)                                           \
        _Pragma("unroll")                                                    \
        for (int nj = 0; nj < NJ; ++nj)                                      \
            acc[(Q) * 4 + mi][nj] =                                          \
                __builtin_amdgcn_mfma_f32_16x16x32_bf16(a[mi], b[nj],        \
                                                        acc[(Q) * 4 + mi][nj], 0, 0, 0); \
    __builtin_amdgcn_s_setprio(0); } while (0)

    // One K-tile in (AD,BD); next tile certified in (AN,BN_); stage ks into (AD,BD).
    // Entry invariant: ds = aX(4)+b0v(NJ); vm = stage(t+1 -> AN,BN_): 4+NJ ops.
#define TILE(AD, BD, AN, BN_, ks) do {                                       \
    LDA4(aY, AD, 4, sw0);            /* ds: 8+NJ */                          \
    w_lgkm4();                       /* aX,b0v ready; aY rides */            \
    MF(0, aX, b0v);                                                          \
    LDA4(aX, AD, 0, sw1);                                                    \
    LDB(b1v, BD, sw1);               /* ds: aY4 + 4+NJ */                    \
    w_lgkm_4nj<NJ>();                /* aY ready */                          \
    MF(1, aY, b0v);                                                          \
    LDA4(aY, AD, 4, sw1);            /* ds: 8+NJ */                          \
    w_lgkm4();                       /* aX,b1v ready */                      \
    MF(0, aX, b1v);                                                          \
    w_lgkm0();                       /* all my (AD,BD) reads done */         \
    barx();                          /* all waves done reading (AD,BD) */    \
    STAGE(ks, AD, BD);               /* vm: old 4+NJ + new 4+NJ */           \
    w_vm_ns<NJ>();                   /* stage(t+1 -> AN,BN_) complete */     \
    barx();                          /* (AN,BN_) certified for all */        \
    LDA4(aX, AN, 0, sw0);                                                    \
    LDB(b0v, BN_, sw0);              /* next-tile kk0 reads in flight */     \
    sched0();                                                                \
    MF(1, aY, b1v);                  /* rides over next-tile reads */        \
} while (0)

    // prologue: stage tiles 0,1; certify tile0; issue tile0 kk0 frags.
    STAGE(0, A0, B0);
    STAGE(1, A1, B1);
    w_vm_ns<NJ>();
    barx();
    LDA4(aX, A0, 0, sw0);
    LDB(b0v, B0, sw0);

    for (int t = 0; t < 32; t += 2) {
        TILE(A0, B0, A1, B1, (t + 2 < 32) ? t + 2 : 31);
        TILE(A1, B1, A0, B0, (t + 3 < 32) ? t + 3 : 31);
    }
    asm volatile("s_waitcnt vmcnt(0) lgkmcnt(0)" ::: "memory");

#undef TILE
#undef STAGE
#undef LDA4
#undef LDB
#undef MF

    // ---- epilogue (pack formulas verbatim; z selected per column for fused tiles)
#pragma unroll
    for (int j = 0; j < NJ; ++j) {
        int n = n0g + wc * (16 * NJ) + j * 16 + l15;    // fused col
        int zj = (MODE == 1) ? (n >> 11) : 0;
        int nn = (MODE == 1) ? (n & 2047) : n;
        float bn = (MODE == 1)
                     ? ((zj == 0) ? bias0[nn] : (zj == 1) ? bias1[nn] : bias2[nn])
                     : bias0[nn];
        unsigned short* Cz = (zj == 0) ? C0 : (zj == 1) ? C1 : C2;
#pragma unroll
        for (int i = 0; i < 8; ++i) {
            int mb = m0 + wr * 128 + i * 16 + quad * 4;   // base row, regs = mb..mb+3
            if (MODE == 1 && zj == 2) {
                // V-pack: 4 regs = 4 consecutive keys (e=0..3) -> one ushort4.
                int b = mb >> 11, s = mb & 2047, h = nn >> 7, d = nn & 127;
                int kt = s >> 4, qv = (s >> 2) & 3, ct = d >> 4, lv = d & 15;
                size_t addr = ((((size_t)((b << 4) + h) * 128 + kt) * 4 + (ct >> 1)) * 4 + qv) * 128
                              + lv * 8 + (ct & 1) * 4;
                ushort4 o;
                o.x = f2bf(acc[i][j][0] + bn);
                o.y = f2bf(acc[i][j][1] + bn);
                o.z = f2bf(acc[i][j][2] + bn);
                o.w = f2bf(acc[i][j][3] + bn);
                *(ushort4*)&Cz[addr] = o;
            } else {
#pragma unroll
                for (int reg = 0; reg < 4; ++reg) {
                    int m = mb + reg;
                    float v = acc[i][j][reg] + bn;
                    if (MODE == 0) {
                        Cf[(size_t)m * HID + nn] = v;
                    } else {
                        int b = m >> 11, s = m & 2047, h = nn >> 7, d = nn & 127;
                        if (zj == 1) {
                            // K-pack: key=s -> (kt, lk); d -> (kk, qk, e)
                            int kt = s >> 4, lk = s & 15, kk = d >> 5, qk = (d >> 3) & 3, e = d & 7;
                            size_t addr = ((((size_t)((b << 4) + h) * 128 + kt) * 4 + kk) * 4 + qk) * 128
                                          + lk * 8 + e;
                            Cz[addr] = f2bf(v);
                        } else {
                            Cz[(size_t)(((b << 4) + h) * S_LEN + s) * HDIM + d] = f2bf(v);
                        }
                    }
                }
            }
        }
    }
}

// ---------------------------------------------------------------- flash attention (R9, unchanged)
__launch_bounds__(256, 4)
__global__ void attn_kernel(const unsigned short* __restrict__ Qg,
                            const unsigned short* __restrict__ Kp,
                            const unsigned short* __restrict__ Vp,
                            unsigned short* __restrict__ O) {
    int linear = blockIdx.y * 32 + blockIdx.x;   // 0..1023
    int xcd = linear & 7;
    int u = linear >> 3;                          // 0..127
    int bh = xcd * 4 + (u & 3);                   // 4 bh per XCD
    int j = u >> 2;                               // 0..31
    int b = bh >> 4, h = bh & 15;

    int tid = threadIdx.x, lane = tid & 63, w = tid >> 6;
    int l15 = lane & 15, quad = lane >> 4;

    int role = (w + (u >> 5)) & 3;                // per-CU-varying rotation
    int strip = (role < 2) ? (2 * j + role) : (126 - 2 * j + (role - 2));
    int r0 = strip * 16;

    const unsigned short* Qb = Qg + (size_t)bh * (S_LEN * HDIM);
    const unsigned short* Kb = Kp + (size_t)bh * 262144 + quad * 128 + l15 * 8;
    const unsigned short* Vb = Vp + (size_t)bh * 262144 + quad * 128 + l15 * 8;

    bf16x8 qf[4];
#pragma unroll
    for (int kk = 0; kk < 4; ++kk)
        qf[kk] = *(const bf16x8*)&Qb[(size_t)(r0 + l15) * HDIM + kk * 32 + quad * 8];

    f32x4 o_acc[8];
#pragma unroll
    for (int c = 0; c < 8; ++c) o_acc[c] = (f32x4){0.f, 0.f, 0.f, 0.f};
    float l_part = 0.f;

    const float k2 = 0.08838834764831845f * 1.4426950408889634f;  // scale*log2(e)

    int nkt = strip + 1;

    bf16x8 kA[4], kB[4], v[4];

#define LOADK(dst, t) do { size_t _o = (size_t)(t) * 2048;                         \
    dst[0] = *(const bf16x8*)&Kb[_o];                                              \
    dst[1] = *(const bf16x8*)&Kb[_o + 512];                                        \
    dst[2] = *(const bf16x8*)&Kb[_o + 1024];                                       \
    dst[3] = *(const bf16x8*)&Kb[_o + 1536]; } while (0)

#define LOADV(dst, t) do { size_t _o = (size_t)(t) * 2048;                         \
    dst[0] = *(const bf16x8*)&Vb[_o];                                              \
    dst[1] = *(const bf16x8*)&Vb[_o + 512];                                        \
    dst[2] = *(const bf16x8*)&Vb[_o + 1024];                                       \
    dst[3] = *(const bf16x8*)&Vb[_o + 1536]; } while (0)

#define VLO(x) __builtin_shufflevector(x, x, 0, 1, 2, 3)
#define VHI(x) __builtin_shufflevector(x, x, 4, 5, 6, 7)

#define TILE(kreg, t) do {                                                         \
    f32x4 st0 = (f32x4){0.f, 0.f, 0.f, 0.f};                                       \
    f32x4 st1 = (f32x4){0.f, 0.f, 0.f, 0.f};                                       \
    st0 = __builtin_amdgcn_mfma_f32_16x16x32_bf16(kreg[0], qf[0], st0, 0, 0, 0);   \
    st1 = __builtin_amdgcn_mfma_f32_16x16x32_bf16(kreg[1], qf[1], st1, 0, 0, 0);   \
    st0 = __builtin_amdgcn_mfma_f32_16x16x32_bf16(kreg[2], qf[2], st0, 0, 0, 0);   \
    st1 = __builtin_amdgcn_mfma_f32_16x16x32_bf16(kreg[3], qf[3], st1, 0, 0, 0);   \
    f32x4 stv = st0 + st1;                                                         \
    float p0, p1, p2, p3;                                                          \
    if ((t) == nkt - 1) {                                                          \
        p0 = (quad * 4 + 0 <= l15) ? exp2f(stv[0] * k2) : 0.f;                     \
        p1 = (quad * 4 + 1 <= l15) ? exp2f(stv[1] * k2) : 0.f;                     \
        p2 = (quad * 4 + 2 <= l15) ? exp2f(stv[2] * k2) : 0.f;                     \
        p3 = (quad * 4 + 3 <= l15) ? exp2f(stv[3] * k2) : 0.f;                     \
    } else {                                                                       \
        p0 = exp2f(stv[0] * k2); p1 = exp2f(stv[1] * k2);                          \
        p2 = exp2f(stv[2] * k2); p3 = exp2f(stv[3] * k2);                          \
    }                                                                              \
    l_part += (p0 + p1) + (p2 + p3);                                               \
    bf16x4 pf;                                                                     \
    pf[0] = (short)f2bf(p0); pf[1] = (short)f2bf(p1);                              \
    pf[2] = (short)f2bf(p2); pf[3] = (short)f2bf(p3);                              \
    o_acc[0] = pv_mfma(pf, VLO(v[0]), o_acc[0]);                                   \
    o_acc[1] = pv_mfma(pf, VHI(v[0]), o_acc[1]);                                   \
    o_acc[2] = pv_mfma(pf, VLO(v[1]), o_acc[2]);                                   \
    o_acc[3] = pv_mfma(pf, VHI(v[1]), o_acc[3]);                                   \
    o_acc[4] = pv_mfma(pf, VLO(v[2]), o_acc[4]);                                   \
    o_acc[5] = pv_mfma(pf, VHI(v[2]), o_acc[5]);                                   \
    o_acc[6] = pv_mfma(pf, VLO(v[3]), o_acc[6]);                                   \
    o_acc[7] = pv_mfma(pf, VHI(v[3]), o_acc[7]);                                   \
} while (0)

    LOADK(kA, 0);
    int kt = 0;
    while (true) {
        int ktn = (kt + 1 < nkt) ? kt + 1 : kt;
        LOADV(v, kt);
        LOADK(kB, ktn);
        TILE(kA, kt);
        if (++kt >= nkt) break;

        ktn = (kt + 1 < nkt) ? kt + 1 : kt;
        LOADV(v, kt);
        LOADK(kA, ktn);
        TILE(kB, kt);
        if (++kt >= nkt) break;
    }

#undef TILE
#undef LOADK
#undef LOADV
#undef VLO
#undef VHI

    l_part += __shfl_xor(l_part, 16, 64);
    l_part += __shfl_xor(l_part, 32, 64);

#pragma unroll
    for (int reg = 0; reg < 4; ++reg) {
        float l = __shfl(l_part, quad * 4 + reg, 64);
        float inv = 1.f / l;
        int srow = r0 + quad * 4 + reg;
        unsigned short* op = O + (size_t)(b * S_LEN + srow) * HID + h * HDIM;
#pragma unroll
        for (int ct = 0; ct < 8; ++ct)
            op[ct * 16 + l15] = f2bf(o_acc[ct][reg] * inv);
    }
}

// ---------------------------------------------------------------- launch
extern "C" void kernel_launch(void* const* d_in, const int* in_sizes, int n_in,
                              void* d_out, int out_size, void* d_ws, size_t ws_size,
                              hipStream_t stream) {
    (void)in_sizes; (void)n_in; (void)out_size; (void)ws_size;
    const float* x  = (const float*)d_in[0];
    const float* wq = (const float*)d_in[2];
    const float* bq = (const float*)d_in[3];
    const float* wk = (const float*)d_in[4];
    const float* bk = (const float*)d_in[5];
    const float* wv = (const float*)d_in[6];
    const float* bv = (const float*)d_in[7];
    const float* wo = (const float*)d_in[8];
    const float* bo = (const float*)d_in[9];
    float* out = (float*)d_out;

    unsigned short* ws = (unsigned short*)d_ws;
    const size_t WSZ = 4194304;
    unsigned short* wqT = ws;                // [0, 4M)   wqT/wkT/wvT contiguous =
    unsigned short* wkT = ws + WSZ;          // [4M, 8M)  fused [6144][2048] B for QKV
    unsigned short* wvT = ws + 2 * WSZ;      // [8M, 12M)
    unsigned short* woT = ws + 3 * WSZ;      // [12M, 16M)
    unsigned short* xb  = ws + 4 * WSZ;      // [16M, 24M)
    unsigned short* Ab  = ws + 4 * WSZ;      // aliases xb (dead after QKV gemm)
    unsigned short* Qb  = ws + 6 * WSZ;      // [24M, 32M)
    unsigned short* Kb  = ws + 8 * WSZ;      // [32M, 40M)  fragment-packed
    unsigned short* Vb  = ws + 10 * WSZ;     // [40M, 48M)  fragment-packed

    convert_x<<<dim3(8192), 256, 0, stream>>>(x, xb);
    convert_wt<<<dim3(32, 32, 4), 256, 0, stream>>>(wq, wk, wv, wo, wqT, wkT, wvT, woT);
    gemmT<1, 3><<<dim3(512), 512, 0, stream>>>(xb, wqT, bq, bk, bv,
                                               Qb, Kb, Vb, nullptr);
    attn_kernel<<<dim3(32, 32), 256, 0, stream>>>(Qb, Kb, Vb, Ab);
    gemmT<0, 2><<<dim3(256), 512, 0, stream>>>(Ab, woT, bo, nullptr, nullptr,
                                               nullptr, nullptr, nullptr, out);
}